// Round 8
// baseline (73.276 us; speedup 1.0000x reference)
//
#include <hip/hip_runtime.h>
#include <hip/hip_bf16.h>

typedef __attribute__((ext_vector_type(8))) short bf16x8;
typedef __attribute__((ext_vector_type(4))) float f32x4;
typedef __attribute__((ext_vector_type(4))) unsigned short u16x4;

#define MFMA16(a, b, c) __builtin_amdgcn_mfma_f32_16x16x32_bf16(a, b, c, 0, 0, 0)

// B=16, S=2048, EMB=512, HEAD_DIM=64
// Q pre-scaled by 0.125 * log2(e): softmax runs in exp2 domain.
#define QSCALE 0.18033688011112042f

#define GLDS16(gp, lp)                                                         \
    __builtin_amdgcn_global_load_lds(                                          \
        (const __attribute__((address_space(1))) void*)(gp),                   \
        (__attribute__((address_space(3))) void*)(lp), 16, 0, 0)

__device__ __forceinline__ short nbf(float f) {
    __hip_bfloat16 h = __float2bfloat16(f);
    return *(short*)&h;
}
__device__ __forceinline__ unsigned short nbfu(float f) {
    __hip_bfloat16 h = __float2bfloat16(f);
    return *(unsigned short*)&h;
}

// Wt[mat][h][e] = bf16(W_mat[e][h])
__global__ void wt_kernel(const float* __restrict__ Wq, const float* __restrict__ Wk,
                          const float* __restrict__ Wv, unsigned short* __restrict__ Wt) {
    const int h = blockIdx.x;
    const int mat = blockIdx.y;
    const int e = threadIdx.x;
    const float* W = (mat == 0) ? Wq : ((mat == 1) ? Wk : Wv);
    Wt[(mat * 64 + h) * 512 + e] = nbfu(W[e * 64 + h]);
}

// Fused QKV projection (unchanged).
__global__ __launch_bounds__(256, 2) void qkv_proj(
    const float* __restrict__ x1, const unsigned short* __restrict__ Wt,
    unsigned short* __restrict__ Q, unsigned short* __restrict__ K,
    unsigned short* __restrict__ Vt)
{
    __shared__ char alds[2][8192];
    __shared__ char blds[2][12288];

    const int tid = threadIdx.x;
    const int w = tid >> 6, lane = tid & 63;
    const int c = lane & 15, g = lane >> 4;
    const int tokB = blockIdx.x * 64;

    const char* x1b = (const char*)x1;
    const char* Wtb = (const char*)Wt;

    const int tA0 = tid >> 3,           qA0 = (tid & 7) ^ (tA0 & 7);
    const int tA1 = (tid + 256) >> 3,   qA1 = (tid & 7) ^ (tA1 & 7);
    const size_t aoff0 = (size_t)(tokB + tA0) * 2048 + qA0 * 16;
    const size_t aoff1 = (size_t)(tokB + tA1) * 2048 + qA1 * 16;

    auto bsrc = [&](int j) -> size_t {
        const int n = j >> 6, c2 = (j >> 2) & 15, g2 = j & 3;
        return (size_t)((n >> 2) * 64 + (n & 3) * 16 + c2) * 1024 + g2 * 16;
    };
    const size_t boff0 = bsrc(tid), boff1 = bsrc(tid + 256), boff2 = bsrc(tid + 512);

    f32x4 acc[12];
#pragma unroll
    for (int n = 0; n < 12; ++n) acc[n] = (f32x4)0.f;

    GLDS16(x1b + aoff0, &alds[0][tid * 16]);
    GLDS16(x1b + aoff1, &alds[0][4096 + tid * 16]);
    GLDS16(Wtb + boff0, &blds[0][tid * 16]);
    GLDS16(Wtb + boff1, &blds[0][4096 + tid * 16]);
    GLDS16(Wtb + boff2, &blds[0][8192 + tid * 16]);

    const int arow = (w * 16 + c) * 128;
    const int aq0 = (((2 * g) ^ (c & 7)) * 16);
    const int aq1 = (((2 * g + 1) ^ (c & 7)) * 16);
    const int brd = (c * 4 + g) * 16;

    int buf = 0;
    for (int ks = 0; ks < 16; ++ks) {
        asm volatile("s_waitcnt vmcnt(0)\n\ts_barrier" ::: "memory");

        if (ks < 15) {
            const size_t ka = (size_t)(ks + 1) * 128;
            const size_t kb = (size_t)(ks + 1) * 64;
            char* ab = &alds[buf ^ 1][0];
            char* bb = &blds[buf ^ 1][0];
            GLDS16(x1b + aoff0 + ka, ab + tid * 16);
            GLDS16(x1b + aoff1 + ka, ab + 4096 + tid * 16);
            GLDS16(Wtb + boff0 + kb, bb + tid * 16);
            GLDS16(Wtb + boff1 + kb, bb + 4096 + tid * 16);
            GLDS16(Wtb + boff2 + kb, bb + 8192 + tid * 16);
        }

        const char* ab = &alds[buf][0];
        const char* bb = &blds[buf][0];
        f32x4 a0 = *(const f32x4*)(ab + arow + aq0);
        f32x4 a1 = *(const f32x4*)(ab + arow + aq1);
        bf16x8 af;
        af[0] = nbf(a0[0]); af[1] = nbf(a0[1]); af[2] = nbf(a0[2]); af[3] = nbf(a0[3]);
        af[4] = nbf(a1[0]); af[5] = nbf(a1[1]); af[6] = nbf(a1[2]); af[7] = nbf(a1[3]);
#pragma unroll
        for (int n = 0; n < 12; ++n) {
            bf16x8 bf = *(const bf16x8*)(bb + n * 1024 + brd);
            acc[n] = MFMA16(af, bf, acc[n]);
        }
        buf ^= 1;
    }

    const int tok0 = tokB + w * 16;
#pragma unroll
    for (int n = 0; n < 4; ++n)
#pragma unroll
        for (int r = 0; r < 4; ++r)
            Q[(size_t)(tok0 + g * 4 + r) * 64 + n * 16 + c] = nbfu(acc[n][r] * QSCALE);
#pragma unroll
    for (int n = 0; n < 4; ++n)
#pragma unroll
        for (int r = 0; r < 4; ++r)
            K[(size_t)(tok0 + g * 4 + r) * 64 + n * 16 + c] = nbfu(acc[4 + n][r]);

    const int b = tok0 >> 11;
    const int sl = (tok0 & 2047) + g * 4;
#pragma unroll
    for (int n = 0; n < 4; ++n) {
        const int d = n * 16 + c;
        u16x4 pv;
#pragma unroll
        for (int r = 0; r < 4; ++r) pv[r] = nbfu(acc[8 + n][r]);
        *(u16x4*)(Vt + ((size_t)(b * 64 + d) << 11) + sl) = pv;
    }
}

// Causal flash attention v6:
//  - two INDEPENDENT softmax streams per iteration (half h0 = keys +0..63,
//    h1 = +64..127): separate m/l/acc, merged in epilogue -> 2x ILP on the
//    serial chain.
//  - zero cross-lane ops in steady state: per-lane partial l (group-reduced
//    once at end); defer-max check via per-lane tile-max + wave-wide __any;
//    group-max shfl reduction only inside the (rare) rescale branch.
//  - same staging/grid as v5b (KBLK=128 double-buffered, lane-ordered
//    fragment layout, XCD batch mapping, complementary-qt pairing).
__global__ __launch_bounds__(256, 2) void flash_attn(
    const unsigned short* __restrict__ Q, const unsigned short* __restrict__ K,
    const unsigned short* __restrict__ Vt, float* __restrict__ out)
{
    __shared__ char kv[2][32768];   // [buf][ K:0..16383 | V:16384..32767 ]
    __shared__ char p_lds[16384];   // [wave][ps=4][lane=64]x16B

    const int tid = threadIdx.x;
    const int w = tid >> 6;
    const int lane = tid & 63;
    const int c = lane & 15, g = lane >> 4;

    const int id = blockIdx.x;
    const int xcd = id & 7;
    const int b = 2 * xcd + ((id >> 3) & 1);    // per-XCD batch pair -> L2-resident K/V
    const int bxx = id >> 4;
    const int qt = (bxx < 16) ? bxx : 47 - bxx; // CU pair (id,id+256): qt sum = 31
    const int qr0c = qt * 64 + w * 16 + c;      // this lane's q row (within batch)
    const size_t qrow_g = ((size_t)b << 11) + qt * 64 + w * 16;

    bf16x8 qf0 = *(const bf16x8*)(Q + (qrow_g + c) * 64 + g * 8);
    bf16x8 qf1 = *(const bf16x8*)(Q + (qrow_g + c) * 64 + 32 + g * 8);

    const char* Kb = (const char*)(K + (((size_t)b << 11) * 64));
    const char* Vb = (const char*)(Vt + (((size_t)b << 11) * 64));   // [d=64][s=2048]

    const int nn = w;
    const int g2 = (tid >> 4) & 3, c2 = tid & 15;
    const size_t ksrc0 = (size_t)(nn * 16 + c2) * 128 + g2 * 16;   // + h*8192 + s*64
    const size_t vsrc0 = (size_t)(nn * 16 + c2) * 4096 + g2 * 16;  // + h*128  + s*64
    const int kdst0 = nn * 1024 + lane * 16;                       // + h*8192 + s*4096
    const int vdst0 = 16384 + kdst0;

    float m0 = -1e30f, l0 = 0.f;   // half 0: per-lane partial l, group-shared m
    float m1 = -1e30f, l1 = 0.f;   // half 1
    f32x4 acc0[4], acc1[4];
#pragma unroll
    for (int n = 0; n < 4; ++n) { acc0[n] = (f32x4)0.f; acc1[n] = (f32x4)0.f; }

    const int n_iter = (qt >> 1) + 1;

    int buf = 0;
    {   // prologue: stage tile 0 into buf 0 (8 GLDS)
        char* d = &kv[0][0];
#pragma unroll
        for (int h = 0; h < 2; ++h)
#pragma unroll
            for (int s = 0; s < 2; ++s) {
                GLDS16(Kb + ksrc0 + h * 8192 + s * 64, d + kdst0 + h * 8192 + s * 4096);
                GLDS16(Vb + vsrc0 + h * 128 + s * 64,  d + vdst0 + h * 8192 + s * 4096);
            }
    }

    for (int kt2 = 0; kt2 < n_iter; ++kt2) {
        asm volatile("s_waitcnt vmcnt(0)\n\ts_barrier" ::: "memory");

        if (kt2 + 1 < n_iter) {
            const size_t ko = (size_t)(kt2 + 1) * 16384;  // 128 key rows x 128 B
            const size_t vo = (size_t)(kt2 + 1) * 256;    // 128 seq elems x 2 B
            char* d = &kv[buf ^ 1][0];
#pragma unroll
            for (int h = 0; h < 2; ++h)
#pragma unroll
                for (int s = 0; s < 2; ++s) {
                    GLDS16(Kb + ko + ksrc0 + h * 8192 + s * 64, d + kdst0 + h * 8192 + s * 4096);
                    GLDS16(Vb + vo + vsrc0 + h * 128 + s * 64,  d + vdst0 + h * 8192 + s * 4096);
                }
        }

        // ---- S^T = K Q^T for both halves (16 ds_read_b128, 16 MFMA) ----
        const char* kb = &kv[buf][0];
        f32x4 s[8];
#pragma unroll
        for (int i = 0; i < 8; ++i) s[i] = (f32x4)0.f;
        __builtin_amdgcn_s_setprio(1);
#pragma unroll
        for (int h = 0; h < 2; ++h)
#pragma unroll
            for (int n = 0; n < 4; ++n) {
                bf16x8 ka0 = *(const bf16x8*)(kb + h * 8192 + n * 1024 + lane * 16);
                bf16x8 ka1 = *(const bf16x8*)(kb + h * 8192 + 4096 + n * 1024 + lane * 16);
                s[h * 4 + n] = MFMA16(ka0, qf0, s[h * 4 + n]);
                s[h * 4 + n] = MFMA16(ka1, qf1, s[h * 4 + n]);
            }
        __builtin_amdgcn_s_setprio(0);

        // ---- causal mask (last iteration only) ----
        if (kt2 == (qt >> 1)) {
#pragma unroll
            for (int h = 0; h < 2; ++h)
#pragma unroll
                for (int n = 0; n < 4; ++n) {
                    const int key0 = kt2 * 128 + h * 64 + n * 16 + g * 4;
#pragma unroll
                    for (int r = 0; r < 4; ++r)
                        if (key0 + r > qr0c) s[h * 4 + n][r] = -1e30f;
                }
        }

        char* pw = &p_lds[w * 4096 + ((g >> 1) * 16 + c) * 16 + (g & 1) * 8];

        // ================= half 0 (keys +0..63) =================
        {
            float tm = -1e30f;
#pragma unroll
            for (int i = 0; i < 4; ++i)
                tm = fmaxf(tm, fmaxf(fmaxf(s[i][0], s[i][1]), fmaxf(s[i][2], s[i][3])));
            if (__any(tm > m0 + 8.f)) {                 // rare: group-max only here
                float gm = tm;
                gm = fmaxf(gm, __shfl_xor(gm, 16, 64));
                gm = fmaxf(gm, __shfl_xor(gm, 32, 64));
                const float mn = fmaxf(m0, gm);
                const float alpha = exp2f(m0 - mn);
                m0 = mn;
                l0 *= alpha;                            // per-lane partial, uniform alpha
                float al[4];
#pragma unroll
                for (int r = 0; r < 4; ++r) al[r] = __shfl(alpha, g * 4 + r, 16);
#pragma unroll
                for (int n = 0; n < 4; ++n)
#pragma unroll
                    for (int r = 0; r < 4; ++r) acc0[n][r] *= al[r];
            }
#pragma unroll
            for (int n = 0; n < 4; ++n) {
                float p0 = exp2f(s[n][0] - m0);
                float p1 = exp2f(s[n][1] - m0);
                float p2 = exp2f(s[n][2] - m0);
                float p3 = exp2f(s[n][3] - m0);
                l0 += (p0 + p1) + (p2 + p3);
                u16x4 pk;
                pk[0] = nbfu(p0); pk[1] = nbfu(p1); pk[2] = nbfu(p2); pk[3] = nbfu(p3);
                *(u16x4*)(pw + (n >> 1) * 1024 + (n & 1) * 512) = pk;
            }
        }
        // ================= half 1 (keys +64..127) =================
        {
            float tm = -1e30f;
#pragma unroll
            for (int i = 4; i < 8; ++i)
                tm = fmaxf(tm, fmaxf(fmaxf(s[i][0], s[i][1]), fmaxf(s[i][2], s[i][3])));
            if (__any(tm > m1 + 8.f)) {
                float gm = tm;
                gm = fmaxf(gm, __shfl_xor(gm, 16, 64));
                gm = fmaxf(gm, __shfl_xor(gm, 32, 64));
                const float mn = fmaxf(m1, gm);
                const float alpha = exp2f(m1 - mn);
                m1 = mn;
                l1 *= alpha;
                float al[4];
#pragma unroll
                for (int r = 0; r < 4; ++r) al[r] = __shfl(alpha, g * 4 + r, 16);
#pragma unroll
                for (int n = 0; n < 4; ++n)
#pragma unroll
                    for (int r = 0; r < 4; ++r) acc1[n][r] *= al[r];
            }
#pragma unroll
            for (int n = 0; n < 4; ++n) {
                float p0 = exp2f(s[4 + n][0] - m1);
                float p1 = exp2f(s[4 + n][1] - m1);
                float p2 = exp2f(s[4 + n][2] - m1);
                float p3 = exp2f(s[4 + n][3] - m1);
                l1 += (p0 + p1) + (p2 + p3);
                u16x4 pk;
                pk[0] = nbfu(p0); pk[1] = nbfu(p1); pk[2] = nbfu(p2); pk[3] = nbfu(p3);
                *(u16x4*)(pw + (2 + (n >> 1)) * 1024 + (n & 1) * 512) = pk;
            }
        }

        // ---- O += P V : acc0 gets ps 0,1 ; acc1 gets ps 2,3 ----
        const char* pr = &p_lds[w * 4096 + lane * 16];
        bf16x8 pf[4];
#pragma unroll
        for (int ps = 0; ps < 4; ++ps) pf[ps] = *(const bf16x8*)(pr + ps * 1024);
        const char* vb = &kv[buf][16384];
        __builtin_amdgcn_s_setprio(1);
#pragma unroll
        for (int n = 0; n < 4; ++n) {
            bf16x8 vf0 = *(const bf16x8*)(vb + n * 1024 + lane * 16);
            bf16x8 vf1 = *(const bf16x8*)(vb + 4096 + n * 1024 + lane * 16);
            bf16x8 vf2 = *(const bf16x8*)(vb + 8192 + n * 1024 + lane * 16);
            bf16x8 vf3 = *(const bf16x8*)(vb + 12288 + n * 1024 + lane * 16);
            acc0[n] = MFMA16(pf[0], vf0, acc0[n]);
            acc0[n] = MFMA16(pf[1], vf1, acc0[n]);
            acc1[n] = MFMA16(pf[2], vf2, acc1[n]);
            acc1[n] = MFMA16(pf[3], vf3, acc1[n]);
        }
        __builtin_amdgcn_s_setprio(0);

        buf ^= 1;
    }

    // ---- epilogue: group-reduce per-lane l partials, merge halves ----
    l0 += __shfl_xor(l0, 16, 64); l0 += __shfl_xor(l0, 32, 64);
    l1 += __shfl_xor(l1, 16, 64); l1 += __shfl_xor(l1, 32, 64);
    const float mF = fmaxf(m0, m1);
    const float a0 = exp2f(m0 - mF);                       // m0 always real
    const float a1 = (m1 > -1e29f) ? exp2f(m1 - mF) : 0.f; // guard fully-masked half
    const float inv = 1.f / (l0 * a0 + l1 * a1);
    const float s0 = a0 * inv, s1 = a1 * inv;
    float s0r[4], s1r[4];
#pragma unroll
    for (int r = 0; r < 4; ++r) {
        s0r[r] = __shfl(s0, g * 4 + r, 16);
        s1r[r] = __shfl(s1, g * 4 + r, 16);
    }
#pragma unroll
    for (int n = 0; n < 4; ++n)
#pragma unroll
        for (int r = 0; r < 4; ++r)
            out[(qrow_g + g * 4 + r) * 64 + n * 16 + c] =
                acc0[n][r] * s0r[r] + acc1[n][r] * s1r[r];
}

extern "C" void kernel_launch(void* const* d_in, const int* in_sizes, int n_in,
                              void* d_out, int out_size, void* d_ws, size_t ws_size,
                              hipStream_t stream) {
    const float* x1 = (const float*)d_in[0];
    const float* Wq = (const float*)d_in[2];
    const float* Wk = (const float*)d_in[3];
    const float* Wv = (const float*)d_in[4];
    float* out = (float*)d_out;

    unsigned short* Wt  = (unsigned short*)d_ws;
    unsigned short* Qw  = (unsigned short*)((char*)d_ws + 196608);
    unsigned short* Kw  = (unsigned short*)((char*)d_ws + 196608 + 4194304);
    unsigned short* Vtw = (unsigned short*)((char*)d_ws + 196608 + 2 * 4194304);

    wt_kernel<<<dim3(64, 3), 512, 0, stream>>>(Wq, Wk, Wv, Wt);
    qkv_proj<<<512, 256, 0, stream>>>(x1, Wt, Qw, Kw, Vtw);
    flash_attn<<<512, 256, 0, stream>>>(Qw, Kw, Vtw, out);
}

// Round 9
// 66.212 us; speedup vs baseline: 1.1067x; 1.1067x over previous
//
#include <hip/hip_runtime.h>
#include <hip/hip_bf16.h>

typedef __attribute__((ext_vector_type(8))) short bf16x8;
typedef __attribute__((ext_vector_type(4))) float f32x4;
typedef __attribute__((ext_vector_type(4))) unsigned short u16x4;

#define MFMA16(a, b, c) __builtin_amdgcn_mfma_f32_16x16x32_bf16(a, b, c, 0, 0, 0)

// B=16, S=2048, EMB=512, HEAD_DIM=64
// Q pre-scaled by 0.125 * log2(e): softmax runs in exp2 domain.
#define QSCALE 0.18033688011112042f

#define GLDS16(gp, lp)                                                         \
    __builtin_amdgcn_global_load_lds(                                          \
        (const __attribute__((address_space(1))) void*)(gp),                   \
        (__attribute__((address_space(3))) void*)(lp), 16, 0, 0)

__device__ __forceinline__ short nbf(float f) {
    __hip_bfloat16 h = __float2bfloat16(f);
    return *(short*)&h;
}
__device__ __forceinline__ unsigned short nbfu(float f) {
    __hip_bfloat16 h = __float2bfloat16(f);
    return *(unsigned short*)&h;
}

// Wt[mat][h][e] = bf16(W_mat[e][h])
__global__ void wt_kernel(const float* __restrict__ Wq, const float* __restrict__ Wk,
                          const float* __restrict__ Wv, unsigned short* __restrict__ Wt) {
    const int h = blockIdx.x;
    const int mat = blockIdx.y;
    const int e = threadIdx.x;
    const float* W = (mat == 0) ? Wq : ((mat == 1) ? Wk : Wv);
    Wt[(mat * 64 + h) * 512 + e] = nbfu(W[e * 64 + h]);
}

// Fused QKV projection (unchanged).
__global__ __launch_bounds__(256, 2) void qkv_proj(
    const float* __restrict__ x1, const unsigned short* __restrict__ Wt,
    unsigned short* __restrict__ Q, unsigned short* __restrict__ K,
    unsigned short* __restrict__ Vt)
{
    __shared__ char alds[2][8192];
    __shared__ char blds[2][12288];

    const int tid = threadIdx.x;
    const int w = tid >> 6, lane = tid & 63;
    const int c = lane & 15, g = lane >> 4;
    const int tokB = blockIdx.x * 64;

    const char* x1b = (const char*)x1;
    const char* Wtb = (const char*)Wt;

    const int tA0 = tid >> 3,           qA0 = (tid & 7) ^ (tA0 & 7);
    const int tA1 = (tid + 256) >> 3,   qA1 = (tid & 7) ^ (tA1 & 7);
    const size_t aoff0 = (size_t)(tokB + tA0) * 2048 + qA0 * 16;
    const size_t aoff1 = (size_t)(tokB + tA1) * 2048 + qA1 * 16;

    auto bsrc = [&](int j) -> size_t {
        const int n = j >> 6, c2 = (j >> 2) & 15, g2 = j & 3;
        return (size_t)((n >> 2) * 64 + (n & 3) * 16 + c2) * 1024 + g2 * 16;
    };
    const size_t boff0 = bsrc(tid), boff1 = bsrc(tid + 256), boff2 = bsrc(tid + 512);

    f32x4 acc[12];
#pragma unroll
    for (int n = 0; n < 12; ++n) acc[n] = (f32x4)0.f;

    GLDS16(x1b + aoff0, &alds[0][tid * 16]);
    GLDS16(x1b + aoff1, &alds[0][4096 + tid * 16]);
    GLDS16(Wtb + boff0, &blds[0][tid * 16]);
    GLDS16(Wtb + boff1, &blds[0][4096 + tid * 16]);
    GLDS16(Wtb + boff2, &blds[0][8192 + tid * 16]);

    const int arow = (w * 16 + c) * 128;
    const int aq0 = (((2 * g) ^ (c & 7)) * 16);
    const int aq1 = (((2 * g + 1) ^ (c & 7)) * 16);
    const int brd = (c * 4 + g) * 16;

    int buf = 0;
    for (int ks = 0; ks < 16; ++ks) {
        asm volatile("s_waitcnt vmcnt(0)\n\ts_barrier" ::: "memory");

        if (ks < 15) {
            const size_t ka = (size_t)(ks + 1) * 128;
            const size_t kb = (size_t)(ks + 1) * 64;
            char* ab = &alds[buf ^ 1][0];
            char* bb = &blds[buf ^ 1][0];
            GLDS16(x1b + aoff0 + ka, ab + tid * 16);
            GLDS16(x1b + aoff1 + ka, ab + 4096 + tid * 16);
            GLDS16(Wtb + boff0 + kb, bb + tid * 16);
            GLDS16(Wtb + boff1 + kb, bb + 4096 + tid * 16);
            GLDS16(Wtb + boff2 + kb, bb + 8192 + tid * 16);
        }

        const char* ab = &alds[buf][0];
        const char* bb = &blds[buf][0];
        f32x4 a0 = *(const f32x4*)(ab + arow + aq0);
        f32x4 a1 = *(const f32x4*)(ab + arow + aq1);
        bf16x8 af;
        af[0] = nbf(a0[0]); af[1] = nbf(a0[1]); af[2] = nbf(a0[2]); af[3] = nbf(a0[3]);
        af[4] = nbf(a1[0]); af[5] = nbf(a1[1]); af[6] = nbf(a1[2]); af[7] = nbf(a1[3]);
#pragma unroll
        for (int n = 0; n < 12; ++n) {
            bf16x8 bf = *(const bf16x8*)(bb + n * 1024 + brd);
            acc[n] = MFMA16(af, bf, acc[n]);
        }
        buf ^= 1;
    }

    const int tok0 = tokB + w * 16;
#pragma unroll
    for (int n = 0; n < 4; ++n)
#pragma unroll
        for (int r = 0; r < 4; ++r)
            Q[(size_t)(tok0 + g * 4 + r) * 64 + n * 16 + c] = nbfu(acc[n][r] * QSCALE);
#pragma unroll
    for (int n = 0; n < 4; ++n)
#pragma unroll
        for (int r = 0; r < 4; ++r)
            K[(size_t)(tok0 + g * 4 + r) * 64 + n * 16 + c] = nbfu(acc[4 + n][r]);

    const int b = tok0 >> 11;
    const int sl = (tok0 & 2047) + g * 4;
#pragma unroll
    for (int n = 0; n < 4; ++n) {
        const int d = n * 16 + c;
        u16x4 pv;
#pragma unroll
        for (int r = 0; r < 4; ++r) pv[r] = nbfu(acc[8 + n][r]);
        *(u16x4*)(Vt + ((size_t)(b * 64 + d) << 11) + sl) = pv;
    }
}

// Causal flash attention v7: in-block split-K.
//  - 512 threads = 8 waves. Set 0 (waves 0-3) handles even 128-key tiles,
//    set 1 (waves 4-7) odd tiles, same 64 q-rows. Heavy block chain: 16 -> 8
//    super-iterations; 2 waves/SIMD overlap the two sets' phases.
//  - Each set: private m/l/acc (per-lane partial l, defer-max); sets merged
//    once at the end via LDS (two-way flash combine, empty-set guard).
//  - Per-tile LDS layouts identical to v5b; pair-buffers kv[2][64KB] + P 32KB
//    = 160KB LDS -> 1 block/CU.
//  - Grid: qt = 31 - (id>>4): heavy 256 blocks first, light backfill descending.
__global__ __launch_bounds__(512, 1) void flash_attn(
    const unsigned short* __restrict__ Q, const unsigned short* __restrict__ K,
    const unsigned short* __restrict__ Vt, float* __restrict__ out)
{
    __shared__ char kv[2][65536];   // [buf][ tileA K 16K | tileA V 16K | tileB K 16K | tileB V 16K ]
    __shared__ char p_lds[32768];   // [wave 0..7][ps=4][lane=64]x16B

    const int tid = threadIdx.x;
    const int W = tid >> 6;         // 0..7
    const int st = W >> 2;          // key-split set
    const int w = W & 3;            // q-row group
    const int lane = tid & 63;
    const int c = lane & 15, g = lane >> 4;

    const int id = blockIdx.x;
    const int b = 2 * (id & 7) + ((id >> 3) & 1);
    const int qt = 31 - (id >> 4);            // heavy blocks dispatch first
    const int n2 = (qt >> 1) + 1;             // # 128-key tiles
    const int J = (n2 + 1) >> 1;              // super-iterations (tile pairs)
    const int qr0c = qt * 64 + w * 16 + c;
    const size_t qrow_g = ((size_t)b << 11) + qt * 64 + w * 16;

    bf16x8 qf0 = *(const bf16x8*)(Q + (qrow_g + c) * 64 + g * 8);
    bf16x8 qf1 = *(const bf16x8*)(Q + (qrow_g + c) * 64 + 32 + g * 8);

    const char* Kb = (const char*)(K + (((size_t)b << 11) * 64));
    const char* Vb = (const char*)(Vt + (((size_t)b << 11) * 64));   // [d=64][s=2048]

    // staging decomposition (v5b chunk math, 512-thread version):
    const int c2 = tid & 15, g2 = (tid >> 4) & 3, nn = (tid >> 6) & 3, s4 = (tid >> 8) & 1;
    const int koff = (nn * 16 + c2) * 128 + g2 * 16 + s4 * 64;    // +8192 for h=1
    const int voff = (nn * 16 + c2) * 4096 + g2 * 16 + s4 * 64;   // +128  for h=1

    float m = -1e30f, l = 0.f;      // per-set: m uniform per row c, l per-lane partial
    f32x4 acc[4];
#pragma unroll
    for (int n = 0; n < 4; ++n) acc[n] = (f32x4)0.f;

    {   // prologue: stage pair 0 into buf 0 (8 GLDS/thread)
        char* d = &kv[0][0];
        GLDS16(Kb + koff,                 d + tid * 16);
        GLDS16(Kb + koff + 8192,          d + 8192 + tid * 16);
        GLDS16(Vb + voff,                 d + 16384 + tid * 16);
        GLDS16(Vb + voff + 128,           d + 16384 + 8192 + tid * 16);
        GLDS16(Kb + 16384 + koff,         d + 32768 + tid * 16);
        GLDS16(Kb + 16384 + koff + 8192,  d + 32768 + 8192 + tid * 16);
        GLDS16(Vb + 256 + voff,           d + 49152 + tid * 16);
        GLDS16(Vb + 256 + voff + 128,     d + 49152 + 8192 + tid * 16);
    }

    for (int j = 0; j < J; ++j) {
        asm volatile("s_waitcnt vmcnt(0)\n\ts_barrier" ::: "memory");

        if (j + 1 < J) {   // stage next pair (tiles 2j+2, 2j+3; always <16 -> in-bounds)
            const size_t kA = (size_t)(2 * j + 2) * 16384;
            const size_t vA = (size_t)(2 * j + 2) * 256;
            char* d = &kv[(j & 1) ^ 1][0];
            GLDS16(Kb + kA + koff,                 d + tid * 16);
            GLDS16(Kb + kA + koff + 8192,          d + 8192 + tid * 16);
            GLDS16(Vb + vA + voff,                 d + 16384 + tid * 16);
            GLDS16(Vb + vA + voff + 128,           d + 16384 + 8192 + tid * 16);
            GLDS16(Kb + kA + 16384 + koff,         d + 32768 + tid * 16);
            GLDS16(Kb + kA + 16384 + koff + 8192,  d + 32768 + 8192 + tid * 16);
            GLDS16(Vb + vA + 256 + voff,           d + 49152 + tid * 16);
            GLDS16(Vb + vA + 256 + voff + 128,     d + 49152 + 8192 + tid * 16);
        }

        const int t = 2 * j + st;          // this set's tile
        if (t < n2) {
            const char* kb = &kv[j & 1][st * 32768];
            const char* vb = kb + 16384;

            // ---- S^T = K Q^T (16 ds_read_b128, 16 MFMA) ----
            f32x4 s[8];
#pragma unroll
            for (int i = 0; i < 8; ++i) s[i] = (f32x4)0.f;
            __builtin_amdgcn_s_setprio(1);
#pragma unroll
            for (int h = 0; h < 2; ++h)
#pragma unroll
                for (int n = 0; n < 4; ++n) {
                    bf16x8 ka0 = *(const bf16x8*)(kb + h * 8192 + n * 1024 + lane * 16);
                    bf16x8 ka1 = *(const bf16x8*)(kb + h * 8192 + 4096 + n * 1024 + lane * 16);
                    s[h * 4 + n] = MFMA16(ka0, qf0, s[h * 4 + n]);
                    s[h * 4 + n] = MFMA16(ka1, qf1, s[h * 4 + n]);
                }
            __builtin_amdgcn_s_setprio(0);

            // ---- causal mask (this set's last tile only) ----
            if (t == n2 - 1) {
#pragma unroll
                for (int h = 0; h < 2; ++h)
#pragma unroll
                    for (int n = 0; n < 4; ++n) {
                        const int key0 = t * 128 + h * 64 + n * 16 + g * 4;
#pragma unroll
                        for (int r = 0; r < 4; ++r)
                            if (key0 + r > qr0c) s[h * 4 + n][r] = -1e30f;
                    }
            }

            // ---- online softmax (exp2 domain, defer-max THR=8) ----
            float tm = -1e30f;
#pragma unroll
            for (int i = 0; i < 8; ++i)
                tm = fmaxf(tm, fmaxf(fmaxf(s[i][0], s[i][1]), fmaxf(s[i][2], s[i][3])));

            if (__any(tm > m + 8.f)) {
                float gm = tm;
                gm = fmaxf(gm, __shfl_xor(gm, 16, 64));
                gm = fmaxf(gm, __shfl_xor(gm, 32, 64));
                const float mn = fmaxf(m, gm);
                const float alpha = exp2f(m - mn);
                m = mn;
                l *= alpha;
                float al[4];
#pragma unroll
                for (int r = 0; r < 4; ++r) al[r] = __shfl(alpha, g * 4 + r, 16);
#pragma unroll
                for (int n = 0; n < 4; ++n)
#pragma unroll
                    for (int r = 0; r < 4; ++r) acc[n][r] *= al[r];
            }

            char* pw = &p_lds[W * 4096 + ((g >> 1) * 16 + c) * 16 + (g & 1) * 8];
#pragma unroll
            for (int h = 0; h < 2; ++h)
#pragma unroll
                for (int n = 0; n < 4; ++n) {
                    const int i = h * 4 + n;
                    float p0 = exp2f(s[i][0] - m);
                    float p1 = exp2f(s[i][1] - m);
                    float p2 = exp2f(s[i][2] - m);
                    float p3 = exp2f(s[i][3] - m);
                    l += (p0 + p1) + (p2 + p3);
                    u16x4 pk;
                    pk[0] = nbfu(p0); pk[1] = nbfu(p1); pk[2] = nbfu(p2); pk[3] = nbfu(p3);
                    *(u16x4*)(pw + (h * 2 + (n >> 1)) * 1024 + (n & 1) * 512) = pk;
                }

            // ---- O += P V ----
            const char* pr = &p_lds[W * 4096 + lane * 16];
            bf16x8 pf[4];
#pragma unroll
            for (int ps = 0; ps < 4; ++ps) pf[ps] = *(const bf16x8*)(pr + ps * 1024);
            __builtin_amdgcn_s_setprio(1);
#pragma unroll
            for (int n = 0; n < 4; ++n) {
#pragma unroll
                for (int ps = 0; ps < 4; ++ps) {
                    bf16x8 vf = *(const bf16x8*)(vb + (ps >> 1) * 8192 + (ps & 1) * 4096 + n * 1024 + lane * 16);
                    acc[n] = MFMA16(pf[ps], vf, acc[n]);
                }
            }
            __builtin_amdgcn_s_setprio(0);
        }
    }

    // ---- epilogue: merge set 1 into set 0 via LDS ----
    __syncthreads();
    float* accb = (float*)&kv[0][0];            // [w=4][row=16][col=64] f32
    float* mb = (float*)&kv[0][16384];          // [w=4][c=16]
    float* lb = (float*)&kv[0][16384 + 256];    // [w=4][c=16]

    if (st == 1) {
        l += __shfl_xor(l, 16, 64);
        l += __shfl_xor(l, 32, 64);
        if (g == 0) { mb[w * 16 + c] = m; lb[w * 16 + c] = l; }
#pragma unroll
        for (int n = 0; n < 4; ++n)
#pragma unroll
            for (int r = 0; r < 4; ++r)
                accb[w * 1024 + (g * 4 + r) * 64 + n * 16 + c] = acc[n][r];
    }
    __syncthreads();

    if (st == 0) {
        l += __shfl_xor(l, 16, 64);
        l += __shfl_xor(l, 32, 64);
        const float m1c = mb[w * 16 + c];
        const float l1c = lb[w * 16 + c];
        const float mF = fmaxf(m, m1c);
        const float a0 = exp2f(m - mF);                        // set 0 always non-empty
        const float a1 = (m1c > -1e29f) ? exp2f(m1c - mF) : 0.f;
        const float inv = 1.f / (l * a0 + l1c * a1);
        const float s0 = a0 * inv, s1 = a1 * inv;
        float s0r[4], s1r[4];
#pragma unroll
        for (int r = 0; r < 4; ++r) {
            s0r[r] = __shfl(s0, g * 4 + r, 16);
            s1r[r] = __shfl(s1, g * 4 + r, 16);
        }
#pragma unroll
        for (int n = 0; n < 4; ++n)
#pragma unroll
            for (int r = 0; r < 4; ++r) {
                const float a1v = accb[w * 1024 + (g * 4 + r) * 64 + n * 16 + c];
                out[(qrow_g + g * 4 + r) * 64 + n * 16 + c] = acc[n][r] * s0r[r] + a1v * s1r[r];
            }
    }
}

extern "C" void kernel_launch(void* const* d_in, const int* in_sizes, int n_in,
                              void* d_out, int out_size, void* d_ws, size_t ws_size,
                              hipStream_t stream) {
    const float* x1 = (const float*)d_in[0];
    const float* Wq = (const float*)d_in[2];
    const float* Wk = (const float*)d_in[3];
    const float* Wv = (const float*)d_in[4];
    float* out = (float*)d_out;

    unsigned short* Wt  = (unsigned short*)d_ws;
    unsigned short* Qw  = (unsigned short*)((char*)d_ws + 196608);
    unsigned short* Kw  = (unsigned short*)((char*)d_ws + 196608 + 4194304);
    unsigned short* Vtw = (unsigned short*)((char*)d_ws + 196608 + 2 * 4194304);

    wt_kernel<<<dim3(64, 3), 512, 0, stream>>>(Wq, Wk, Wv, Wt);
    qkv_proj<<<512, 256, 0, stream>>>(x1, Wt, Qw, Kw, Vtw);
    flash_attn<<<512, 512, 0, stream>>>(Qw, Kw, Vtw, out);
}